// Round 1
// baseline (571.479 us; speedup 1.0000x reference)
//
#include <hip/hip_runtime.h>
#include <hip/hip_bf16.h>
#include <stdint.h>

#define LROW 25600
#define NCH 256
#define LN_EPS 1e-5f

typedef float f32x4 __attribute__((ext_vector_type(4)));
typedef __bf16 bf16x8 __attribute__((ext_vector_type(8)));
typedef __bf16 bf16x4 __attribute__((ext_vector_type(4)));

__device__ __forceinline__ void gload_lds16(const void* g, void* l) {
  __builtin_amdgcn_global_load_lds(
      (const __attribute__((address_space(1))) void*)(uintptr_t)g,
      (__attribute__((address_space(3))) void*)(uint32_t)(uintptr_t)l,
      16, 0, 0);
}

__device__ __forceinline__ bf16x8 cvt8(f32x4 a, f32x4 b) {
  bf16x8 r;
  r[0] = (__bf16)a[0]; r[1] = (__bf16)a[1]; r[2] = (__bf16)a[2]; r[3] = (__bf16)a[3];
  r[4] = (__bf16)b[0]; r[5] = (__bf16)b[1]; r[6] = (__bf16)b[2]; r[7] = (__bf16)b[3];
  return r;
}

// ---------------------------------------------------------------------------
// Kernel A: per-batch Grams  G = Xq Xk^T, Gkk = Xk Xk^T  (+ row sums sq, sk)
// 256 wgs: (8 batches) x (21 G-slices + 11 Gkk-slices).  8 waves, 256x256
// output tile per wg, KC=32 fp32 chunks double-buffered in LDS via
// global_load_lds (source-pre-swizzled), counted vmcnt, bf16 cvt at frag load.
// ---------------------------------------------------------------------------
__global__ __launch_bounds__(512, 2) void gram_k(
    const float* __restrict__ qg, const float* __restrict__ kg,
    float* __restrict__ G, float* __restrict__ Gkk,
    float* __restrict__ sq, float* __restrict__ sk) {
  __shared__ __align__(16) float lA[2][8192];
  __shared__ __align__(16) float lB[2][8192];
  const int bid = blockIdx.x;
  const int b = bid >> 5;
  const int s = bid & 31;
  const int mat = (s < 21) ? 0 : 1;
  const int idx = mat ? (s - 21) : s;
  const int parts = mat ? 11 : 21;
  const int c0 = (800 * idx) / parts;
  const int c1 = (800 * (idx + 1)) / parts;
  const int tid = threadIdx.x;
  const int w = tid >> 6, lane = tid & 63;
  const float* Ag = (mat ? kg : qg) + (size_t)b * NCH * LROW;
  const float* Bg = kg + (size_t)b * NCH * LROW;
  float* Gout = (mat ? Gkk : G) + (size_t)b * NCH * NCH;
  float* sums = (mat ? sk : sq) + b * NCH;

  const int rb = w >> 1, chh = w & 1;

  const f32x4 zero = {0.f, 0.f, 0.f, 0.f};
  f32x4 acc[2][4][4];
#pragma unroll
  for (int t = 0; t < 2; ++t)
#pragma unroll
    for (int i = 0; i < 4; ++i)
#pragma unroll
      for (int j = 0; j < 4; ++j) acc[t][i][j] = zero;

  // global source column-unit (16B) pre-swizzled so linear LDS dest ends up
  // XOR-swizzled: LDS[row][u] = global[row][u ^ (row&7)]
  const int cu = (lane & 7) ^ (lane >> 3);

  auto stage = [&](int c, int d) {
#pragma unroll
    for (int i = 0; i < 4; ++i) {
      const int row = (w * 4 + i) * 8 + (lane >> 3);
      gload_lds16(Ag + (size_t)row * LROW + c * 32 + cu * 4, &lA[d][(w * 4 + i) * 256]);
    }
    if (mat == 0) {
#pragma unroll
      for (int i = 0; i < 4; ++i) {
        const int row = (w * 4 + i) * 8 + (lane >> 3);
        gload_lds16(Bg + (size_t)row * LROW + c * 32 + cu * 4, &lB[d][(w * 4 + i) * 256]);
      }
    }
  };

  float rsum = 0.f;
  const int nc = c1 - c0;
  stage(c0, 0);
  for (int cc = 0; cc < nc; ++cc) {
    const int buf = cc & 1;
    const bool pf = (cc + 1 < nc);
    if (pf) stage(c0 + cc + 1, buf ^ 1);
    if (mat == 0) {
      if (pf) asm volatile("s_waitcnt vmcnt(8)" ::: "memory");
      else    asm volatile("s_waitcnt vmcnt(0)" ::: "memory");
    } else {
      if (pf) asm volatile("s_waitcnt vmcnt(4)" ::: "memory");
      else    asm volatile("s_waitcnt vmcnt(0)" ::: "memory");
    }
    __builtin_amdgcn_s_barrier();
    __builtin_amdgcn_sched_barrier(0);

    // exact fp32 row sums (A panel) - permutation within row is sum-invariant
    {
      const int row = tid >> 1;
      const int ub = (tid & 1) * 4;
#pragma unroll
      for (int u = 0; u < 4; ++u) {
        f32x4 v = *(const f32x4*)&lA[buf][row * 32 + (ub + u) * 4];
        rsum += v[0] + v[1] + v[2] + v[3];
      }
    }

    bf16x8 a[4];
#pragma unroll
    for (int i = 0; i < 4; ++i) {
      const int row = rb * 64 + i * 16 + (lane & 15);
      const int u0 = (lane >> 4) * 2;
      const int s0 = u0 ^ (row & 7), s1 = (u0 + 1) ^ (row & 7);
      f32x4 f0 = *(const f32x4*)&lA[buf][row * 32 + s0 * 4];
      f32x4 f1 = *(const f32x4*)&lA[buf][row * 32 + s1 * 4];
      a[i] = cvt8(f0, f1);
    }
    const float(*lBp)[8192] = mat ? lA : lB;
#pragma unroll
    for (int t = 0; t < 2; ++t) {
#pragma unroll
      for (int j = 0; j < 4; ++j) {
        const int row = chh * 128 + t * 64 + j * 16 + (lane & 15);
        const int u0 = (lane >> 4) * 2;
        const int s0 = u0 ^ (row & 7), s1 = (u0 + 1) ^ (row & 7);
        f32x4 f0 = *(const f32x4*)&lBp[buf][row * 32 + s0 * 4];
        f32x4 f1 = *(const f32x4*)&lBp[buf][row * 32 + s1 * 4];
        bf16x8 bfrag = cvt8(f0, f1);
#pragma unroll
        for (int i = 0; i < 4; ++i)
          acc[t][i][j] = __builtin_amdgcn_mfma_f32_16x16x32_bf16(a[i], bfrag, acc[t][i][j], 0, 0, 0);
      }
    }
    asm volatile("s_waitcnt lgkmcnt(0)" ::: "memory");
    __builtin_amdgcn_s_barrier();
    __builtin_amdgcn_sched_barrier(0);
  }

  atomicAdd(&sums[tid >> 1], rsum);
#pragma unroll
  for (int t = 0; t < 2; ++t)
#pragma unroll
    for (int i = 0; i < 4; ++i)
#pragma unroll
      for (int j = 0; j < 4; ++j) {
        const int col = chh * 128 + t * 64 + j * 16 + (lane & 15);
        const int row0 = rb * 64 + i * 16 + (lane >> 4) * 4;
#pragma unroll
        for (int r = 0; r < 4; ++r)
          atomicAdd(&Gout[(row0 + r) * NCH + col], acc[t][i][j][r]);
      }
}

// ---------------------------------------------------------------------------
// Kernel B1: per (batch, head): scores -> softmax -> M = A*Wv_h, cvec = A*bv_h
// ---------------------------------------------------------------------------
__global__ __launch_bounds__(256) void attn_k(
    const float* __restrict__ G, const float* __restrict__ sq,
    const float* __restrict__ sk,
    const float* __restrict__ Wq, const float* __restrict__ bq,
    const float* __restrict__ Wk, const float* __restrict__ bk,
    const float* __restrict__ Wv, const float* __restrict__ bv,
    float* __restrict__ M, float* __restrict__ cvec) {
  __shared__ float Wql[32][257];
  __shared__ float Wkl[32][257];
  __shared__ float QGl[32][257];
  __shared__ float Sl[32][33];
  __shared__ float Al[32][33];
  __shared__ float ul[32], wl[32];
  const int b = blockIdx.x >> 3, h = blockIdx.x & 7;
  const int t = threadIdx.x;
  const float* Gb = G + (size_t)b * 65536;

  for (int i = 0; i < 32; ++i) {
    int idx = i * 256 + t;
    int d = idx >> 8, c = idx & 255;
    Wql[d][c] = Wq[(h * 32 + d) * 256 + c];
    Wkl[d][c] = Wk[(h * 32 + d) * 256 + c];
  }
  __syncthreads();
  {  // QG[d][c'] = sum_c Wq_h[d][c] * G[c][c'] ; thread = c'
    float a[32];
#pragma unroll
    for (int d = 0; d < 32; ++d) a[d] = 0.f;
    for (int c = 0; c < 256; ++c) {
      float g = Gb[c * 256 + t];
#pragma unroll
      for (int d = 0; d < 32; ++d) a[d] += Wql[d][c] * g;
    }
    for (int d = 0; d < 32; ++d) QGl[d][t] = a[d];
  }
  if (t < 32) {
    float u = 0.f, wv = 0.f;
    for (int c = 0; c < 256; ++c) {
      u += Wql[t][c] * sq[b * 256 + c];
      wv += Wkl[t][c] * sk[b * 256 + c];
    }
    ul[t] = u; wl[t] = wv;
  }
  __syncthreads();
  for (int i = 0; i < 4; ++i) {
    int idx = i * 256 + t;
    int d = idx >> 5, e = idx & 31;
    float sv = 0.f;
    for (int c = 0; c < 256; ++c) sv += QGl[d][c] * Wkl[e][c];
    float bqd = bq[h * 32 + d], bke = bk[h * 32 + e];
    Sl[d][e] = (sv + ul[d] * bke + bqd * wl[e] + 25600.f * bqd * bke) * (1.f / 16.f);
  }
  __syncthreads();
  if (t < 32) {
    float m = -1e30f;
    for (int e = 0; e < 32; ++e) m = fmaxf(m, Sl[t][e]);
    float ssum = 0.f;
    for (int e = 0; e < 32; ++e) { float p = __expf(Sl[t][e] - m); Al[t][e] = p; ssum += p; }
    float is = 1.f / ssum;
    for (int e = 0; e < 32; ++e) Al[t][e] *= is;
  }
  __syncthreads();
  {  // M_h rows
    float a[32];
#pragma unroll
    for (int d = 0; d < 32; ++d) a[d] = 0.f;
    for (int e = 0; e < 32; ++e) {
      float wv = Wv[(h * 32 + e) * 256 + t];
#pragma unroll
      for (int d = 0; d < 32; ++d) a[d] += Al[d][e] * wv;
    }
    for (int d = 0; d < 32; ++d) M[((size_t)b * 256 + h * 32 + d) * 256 + t] = a[d];
  }
  if (t < 32) {
    float cv = 0.f;
    for (int e = 0; e < 32; ++e) cv += Al[t][e] * bv[h * 32 + e];
    cvec[b * 256 + h * 32 + t] = cv;
  }
}

// ---------------------------------------------------------------------------
// Kernel B2: LN stats via quadratic form  qf[c] = M[c,:] Gkk M[c,:]^T
// ---------------------------------------------------------------------------
__global__ __launch_bounds__(256) void stats_k(
    const float* __restrict__ Gkk, const float* __restrict__ M,
    const float* __restrict__ sk, const float* __restrict__ cvec,
    float* __restrict__ mu, float* __restrict__ inv) {
  __shared__ float Ml[32][257];
  __shared__ float Ql[32][257];
  const int b = blockIdx.x >> 3, cb = blockIdx.x & 7;
  const int t = threadIdx.x;
  const float* Gk = Gkk + (size_t)b * 65536;
  for (int i = 0; i < 32; ++i) {
    int idx = i * 256 + t;
    Ml[idx >> 8][idx & 255] = M[((size_t)b * 256 + cb * 32 + (idx >> 8)) * 256 + (idx & 255)];
  }
  __syncthreads();
  {
    float a[32];
#pragma unroll
    for (int c = 0; c < 32; ++c) a[c] = 0.f;
    for (int cc = 0; cc < 256; ++cc) {
      float g = Gk[cc * 256 + t];
#pragma unroll
      for (int c = 0; c < 32; ++c) a[c] += Ml[c][cc] * g;
    }
    for (int c = 0; c < 32; ++c) Ql[c][t] = a[c];
  }
  __syncthreads();
  if (t < 32) {
    float qf = 0.f, msk = 0.f;
    for (int j = 0; j < 256; ++j) {
      qf += Ql[t][j] * Ml[t][j];
      msk += Ml[t][j] * sk[b * 256 + j];
    }
    int c = cb * 32 + t;
    float cv = cvec[b * 256 + c];
    float muv = msk * (1.f / 25600.f) + cv;
    float sum2 = qf + 2.f * cv * msk + 25600.f * cv * cv;
    float var = sum2 * (1.f / 25600.f) - muv * muv;
    mu[b * 256 + c] = muv;
    inv[b * 256 + c] = rsqrtf(var + LN_EPS);
  }
}

// ---------------------------------------------------------------------------
// Kernel B3: P = (Wo o inv) M  (bf16), t1, wsum
// ---------------------------------------------------------------------------
__global__ __launch_bounds__(256) void pmat_k(
    const float* __restrict__ M, const float* __restrict__ Wo,
    const float* __restrict__ inv, const float* __restrict__ cvec,
    const float* __restrict__ mu, __bf16* __restrict__ Pb,
    float* __restrict__ t1, float* __restrict__ wsum) {
  __shared__ float Wol[32][257];
  __shared__ float invl[256];
  const int b = blockIdx.x >> 3, ob = blockIdx.x & 7;
  const int t = threadIdx.x;
  invl[t] = inv[b * 256 + t];
  __syncthreads();
  for (int i = 0; i < 32; ++i) {
    int idx = i * 256 + t;
    int o = idx >> 8, c = idx & 255;
    Wol[o][c] = Wo[(ob * 32 + o) * 256 + c] * invl[c];
  }
  __syncthreads();
  {
    float a[32];
#pragma unroll
    for (int o = 0; o < 32; ++o) a[o] = 0.f;
    for (int c = 0; c < 256; ++c) {
      float m = M[((size_t)b * 256 + c) * 256 + t];
#pragma unroll
      for (int o = 0; o < 32; ++o) a[o] += Wol[o][c] * m;
    }
    for (int o = 0; o < 32; ++o)
      Pb[((size_t)b * 256 + ob * 32 + o) * 256 + t] = (__bf16)a[o];
  }
  if (t < 32) {
    float s1 = 0.f, s2 = 0.f;
    for (int c = 0; c < 256; ++c) {
      s1 += Wol[t][c] * (cvec[b * 256 + c] - mu[b * 256 + c]);
      s2 += Wo[(ob * 32 + t) * 256 + c];
    }
    t1[b * 256 + ob * 32 + t] = s1;
    wsum[b * 256 + ob * 32 + t] = s2;
  }
}

// ---------------------------------------------------------------------------
// Kernel C: out = gamma[l]*(P Xk + t1) + beta[l]*wsum + bo  (fused LN + conv)
// 800 wgs: (batch, l-tile of 256).  B-tile transpose-staged to swizzled LDS.
// ---------------------------------------------------------------------------
__global__ __launch_bounds__(512, 2) void out_k(
    const float* __restrict__ key, const __bf16* __restrict__ Pb,
    const float* __restrict__ t1, const float* __restrict__ wsum,
    const float* __restrict__ bo, const float* __restrict__ gamma,
    const float* __restrict__ beta, float* __restrict__ out) {
  __shared__ __align__(16) __bf16 Bt[256 * 256];  // [l][c], XOR-swizzled, 128KB
  const int bid = blockIdx.x;
  const int b = bid / 100, tt = bid % 100;
  const int l0 = tt * 256;
  const int tid = threadIdx.x, w = tid >> 6, lane = tid & 63;
  const float* Kb = key + (size_t)b * NCH * LROW;

  for (int i = 0; i < 32; ++i) {
    int idx = i * 512 + tid;
    int l = idx & 255, cq = idx >> 8;  // cq in [0,64): 4 channels each
    float x0 = Kb[(size_t)(cq * 4 + 0) * LROW + l0 + l];
    float x1 = Kb[(size_t)(cq * 4 + 1) * LROW + l0 + l];
    float x2 = Kb[(size_t)(cq * 4 + 2) * LROW + l0 + l];
    float x3 = Kb[(size_t)(cq * 4 + 3) * LROW + l0 + l];
    bf16x4 hv;
    hv[0] = (__bf16)x0; hv[1] = (__bf16)x1; hv[2] = (__bf16)x2; hv[3] = (__bf16)x3;
    int unit = cq >> 1;
    int byteoff = l * 512 + (((unit ^ (l & 7))) << 4) + (cq & 1) * 8;
    *(bf16x4*)((char*)Bt + byteoff) = hv;
  }
  __syncthreads();

  const int rb = w >> 1, chh = w & 1;
  const f32x4 zero = {0.f, 0.f, 0.f, 0.f};
  f32x4 acc[2][4][4];
#pragma unroll
  for (int t = 0; t < 2; ++t)
#pragma unroll
    for (int i = 0; i < 4; ++i)
#pragma unroll
      for (int j = 0; j < 4; ++j) acc[t][i][j] = zero;

#pragma unroll
  for (int ks = 0; ks < 8; ++ks) {
    bf16x8 a[4];
#pragma unroll
    for (int i = 0; i < 4; ++i) {
      const int row = rb * 64 + i * 16 + (lane & 15);
      a[i] = *(const bf16x8*)(Pb + ((size_t)b * 256 + row) * 256 + ks * 32 + (lane >> 4) * 8);
    }
#pragma unroll
    for (int t = 0; t < 2; ++t) {
#pragma unroll
      for (int j = 0; j < 4; ++j) {
        const int col = chh * 128 + t * 64 + j * 16 + (lane & 15);
        const int unit = ks * 4 + (lane >> 4);
        const int byteoff = col * 512 + ((unit ^ (col & 7)) << 4);
        bf16x8 bfrag = *(const bf16x8*)((const char*)Bt + byteoff);
#pragma unroll
        for (int i = 0; i < 4; ++i)
          acc[t][i][j] = __builtin_amdgcn_mfma_f32_16x16x32_bf16(a[i], bfrag, acc[t][i][j], 0, 0, 0);
      }
    }
  }

  float t1r[4][4], wsr[4][4], bor[4][4];
#pragma unroll
  for (int i = 0; i < 4; ++i)
#pragma unroll
    for (int r = 0; r < 4; ++r) {
      const int row = rb * 64 + i * 16 + (lane >> 4) * 4 + r;
      t1r[i][r] = t1[b * 256 + row];
      wsr[i][r] = wsum[b * 256 + row];
      bor[i][r] = bo[row];
    }
#pragma unroll
  for (int t = 0; t < 2; ++t)
#pragma unroll
    for (int j = 0; j < 4; ++j) {
      const int col = chh * 128 + t * 64 + j * 16 + (lane & 15);
      const float gm = gamma[l0 + col];
      const float bt = beta[l0 + col];
#pragma unroll
      for (int i = 0; i < 4; ++i) {
        const int row0 = rb * 64 + i * 16 + (lane >> 4) * 4;
#pragma unroll
        for (int r = 0; r < 4; ++r) {
          const int row = row0 + r;
          float v = gm * (acc[t][i][j][r] + t1r[i][r]) + bt * wsr[i][r] + bor[i][r];
          out[((size_t)b * 256 + row) * LROW + l0 + col] = v;
        }
      }
    }
}

// ---------------------------------------------------------------------------
extern "C" void kernel_launch(void* const* d_in, const int* in_sizes, int n_in,
                              void* d_out, int out_size, void* d_ws, size_t ws_size,
                              hipStream_t stream) {
  const float* query = (const float*)d_in[0];
  const float* key   = (const float*)d_in[1];
  const float* Wq = (const float*)d_in[2];
  const float* bq = (const float*)d_in[3];
  const float* Wk = (const float*)d_in[4];
  const float* bk = (const float*)d_in[5];
  const float* Wv = (const float*)d_in[6];
  const float* bv = (const float*)d_in[7];
  const float* Wo = (const float*)d_in[8];
  const float* bo = (const float*)d_in[9];
  const float* gamma = (const float*)d_in[10];
  const float* beta  = (const float*)d_in[11];
  float* out = (float*)d_out;

  float* ws = (float*)d_ws;
  float* G    = ws;              // 8*256*256
  float* Gkk  = G + 524288;      // 8*256*256
  float* sq   = Gkk + 524288;    // 8*256
  float* sk   = sq + 2048;       // 8*256
  float* M    = sk + 2048;       // 8*256*256
  float* cvec = M + 524288;      // 8*256
  float* mu   = cvec + 2048;     // 8*256
  float* inv  = mu + 2048;       // 8*256
  float* t1   = inv + 2048;      // 8*256
  float* wsum = t1 + 2048;       // 8*256
  __bf16* Pb  = (__bf16*)(wsum + 2048);  // 8*256*256 bf16

  // zero atomic-accumulated buffers (G, Gkk, sq, sk)
  hipMemsetAsync(d_ws, 0, (size_t)(524288 * 2 + 4096) * sizeof(float), stream);

  gram_k<<<256, 512, 0, stream>>>(query, key, G, Gkk, sq, sk);
  attn_k<<<64, 256, 0, stream>>>(G, sq, sk, Wq, bq, Wk, bk, Wv, bv, M, cvec);
  stats_k<<<64, 256, 0, stream>>>(Gkk, M, sk, cvec, mu, inv);
  pmat_k<<<64, 256, 0, stream>>>(M, Wo, inv, cvec, mu, Pb, t1, wsum);
  out_k<<<800, 512, 0, stream>>>(key, Pb, t1, wsum, bo, gamma, beta, out);
}